// Round 8
// baseline (3222.374 us; speedup 1.0000x reference)
//
#include <hip/hip_runtime.h>
#include <cstdint>
#include <cstddef>

#define ZB 512
#define ZT 256
#define ZIN 64
#define ZEH 128
#define ZH 512
#define ZG 2048
#define ZNC 8

typedef __attribute__((ext_vector_type(8))) short s8v;
typedef __attribute__((ext_vector_type(4))) float f4v;
typedef unsigned short u16;
typedef unsigned int u32;
typedef unsigned long long u64;

__device__ __forceinline__ u16 f2bf(float f){
  u32 u = __builtin_bit_cast(u32, f);
  u += 0x7FFFu + ((u >> 16) & 1u);
  return (u16)(u >> 16);
}
__device__ __forceinline__ s8v pair2v(u64 a, u64 b){
  union { u64 q[2]; s8v v; } u; u.q[0] = a; u.q[1] = b; return u.v;
}
// h layout: [buf][bg][mt][hg][16 rows][16 cols] u16; chunk = 512B contiguous
__device__ __forceinline__ u64 qoffB(int buf, int bg, int mt, int hg){
  return ((((u64)buf * 8 + bg) * 4 + mt) * 32 + hg) * 512;   // BYTES
}
__device__ __forceinline__ u64 aload(const u64* p){
  return __hip_atomic_load(p, __ATOMIC_RELAXED, __HIP_MEMORY_SCOPE_AGENT);
}

// ---- inline-asm memory ops (ALL main-loop VMEM goes through these) --------
#define GLOAD4S(dst, addr, OFF) \
  asm volatile("global_load_dwordx4 %0, %1, off offset:" #OFF " sc0 sc1" : "=v"(dst) : "v"(addr))
#define GLOAD4P(dst, addr, OFF) \
  asm volatile("global_load_dwordx4 %0, %1, off offset:" #OFF : "=v"(dst) : "v"(addr))
#define GLOADF(dst, addr) \
  asm volatile("global_load_dword %0, %1, off sc0 sc1" : "=v"(dst) : "v"(addr))
#define GSTORE2S(addr, val, OFF) \
  asm volatile("global_store_dwordx2 %0, %1, off offset:" #OFF " sc0 sc1" :: "v"(addr), "v"(val))
#define GSTOREF(addr, val) \
  asm volatile("global_store_dword %0, %1, off sc0 sc1" :: "v"(addr), "v"(val))
#define WAITV(N) do{ asm volatile("s_waitcnt vmcnt(" #N ")" ::: "memory"); \
                     __builtin_amdgcn_sched_barrier(0); }while(0)

// ---------------------------------------------------------------------------
// Fold: Wc[2048][128] = W_ih @ W2 (bf16), bc[2048] = W_ih@b2 + b_ih + b_hh
// ---------------------------------------------------------------------------
__global__ __launch_bounds__(128)
void k_fold(const float* __restrict__ W_ih, const float* __restrict__ W2,
            const float* __restrict__ b2, const float* __restrict__ b_ih,
            const float* __restrict__ b_hh, u16* __restrict__ Wc,
            float* __restrict__ bc)
{
  const int r = blockIdx.x, c = threadIdx.x;
  const float* wr = W_ih + (size_t)r * ZH;
  float acc = 0.f;
  for (int k = 0; k < ZH; ++k) acc += wr[k] * W2[(size_t)k * ZEH + c];
  Wc[(size_t)r * ZEH + c] = f2bf(acc);
  __shared__ float red[128];
  float p = 0.f;
  for (int k = c; k < ZH; k += 128) p += wr[k] * b2[k];
  red[c] = p; __syncthreads();
  for (int s = 64; s > 0; s >>= 1){ if (c < s) red[c] += red[c + s]; __syncthreads(); }
  if (c == 0) bc[r] = red[0] + b_ih[r] + b_hh[r];
}

__global__ __launch_bounds__(256)
void k_cvt(const float* __restrict__ src, u16* __restrict__ dst, int n)
{
  int i = blockIdx.x * 256 + threadIdx.x;
  if (i < n) dst[i] = f2bf(src[i]);
}

// ---------------------------------------------------------------------------
// Encoder layer 1: X1 (t-major: [T][B][128]) = bf16(LeakyReLU(seq@W1^T+b1))
// ---------------------------------------------------------------------------
__global__ __launch_bounds__(256)
void k_enc(const float* __restrict__ seq, const float* __restrict__ W1,
           const float* __restrict__ b1, u16* __restrict__ X1)
{
  __shared__ float w1s[ZEH * 65];
  __shared__ float sqs[64 * 65];
  const int tid = threadIdx.x;
  const size_t rb = (size_t)blockIdx.x * 64;
  for (int i = tid; i < ZEH * ZIN; i += 256){ int r = i >> 6, c = i & 63; w1s[r * 65 + c] = W1[i]; }
  for (int i = tid; i < 64 * ZIN; i += 256){ int r = i >> 6, c = i & 63; sqs[r * 65 + c] = seq[(rb + r) * ZIN + c]; }
  __syncthreads();
  const int cg = tid & 31, rg = tid >> 5;
  float acc[8][4];
  #pragma unroll
  for (int i = 0; i < 8; ++i){
    #pragma unroll
    for (int j = 0; j < 4; ++j) acc[i][j] = 0.f;
  }
  for (int k = 0; k < ZIN; ++k){
    float wv[4], sv[8];
    #pragma unroll
    for (int j = 0; j < 4; ++j) wv[j] = w1s[(cg * 4 + j) * 65 + k];
    #pragma unroll
    for (int i = 0; i < 8; ++i) sv[i] = sqs[(rg * 8 + i) * 65 + k];
    #pragma unroll
    for (int i = 0; i < 8; ++i){
      #pragma unroll
      for (int j = 0; j < 4; ++j) acc[i][j] += sv[i] * wv[j];
    }
  }
  #pragma unroll
  for (int i = 0; i < 8; ++i){
    ushort4 pk;
    float v0 = acc[i][0] + b1[cg * 4 + 0]; v0 = v0 > 0.f ? v0 : 0.01f * v0;
    float v1 = acc[i][1] + b1[cg * 4 + 1]; v1 = v1 > 0.f ? v1 : 0.01f * v1;
    float v2 = acc[i][2] + b1[cg * 4 + 2]; v2 = v2 > 0.f ? v2 : 0.01f * v2;
    float v3 = acc[i][3] + b1[cg * 4 + 3]; v3 = v3 > 0.f ? v3 : 0.01f * v3;
    pk.x = f2bf(v0); pk.y = f2bf(v1); pk.z = f2bf(v2); pk.w = f2bf(v3);
    int rf = (int)rb + rg * 8 + i;            // flat b*T + t
    int b = rf >> 8, tt = rf & 255;
    *(ushort4*)(X1 + ((size_t)tt * ZB + b) * ZEH + cg * 4) = pk;
  }
}

// slow-path flag poll (self-contained waits; only makes later vmcnt waits
// more conservative, never less)
__device__ __forceinline__ void pollwait(u64 alo, u64 ahi, u32 target)
{
  long long g = 0;
  for (;;){
    u32 a, b;
    asm volatile("global_load_dword %0, %2, off sc0 sc1\n\t"
                 "global_load_dword %1, %3, off sc0 sc1\n\t"
                 "s_waitcnt vmcnt(0)"
                 : "=v"(a), "=v"(b) : "v"(alo), "v"(ahi) : "memory");
    __builtin_amdgcn_sched_barrier(0);
    if ((__ballot(a >= target) & __ballot(b >= target)) == ~0ull) return;
    __builtin_amdgcn_s_sleep(1);
    if (++g > (1LL << 20)) return;   // fail loud (wrong answer), never hang
  }
}

// ---------------------------------------------------------------------------
// Barrier-free dataflow LSTM. 256 blocks x 256 thr = 1024 independent waves
// (bg 0..7, hg 0..31, w 0..3). Each wave: W_hh/Wc slice in registers, h
// fragments fetched global->register (coalesced 1KB/instr, sc0 sc1), no LDS,
// no block barriers. Per-slot (t,mt) choreography, all VMEM inline-asm with
// hand-counted in-order vmcnt (m135 semantics):
//   C: vmcnt(25)  -> prefetched flags (E of m-1) ready; check, poll on miss
//   E: 2 flag loads (for check at m+1)   D: 16 h loads (h used at m+1)
//   F: 4 X loads (X used at m+1)
//   G: vmcnt(27)  -> h(m)=D(m-1) and X(m)=F(m-1) landed
//   compute: 16+4 MFMA + LSTM cell; S: 4 h stores (sc1, fire-and-forget)
//   A': vmcnt(27) -> S(m-1) acked at MALL;  B': publish flag for quarter m-1
// Flags: flags[bg][mt][hg*4+w], 64B padded; value v = "h_v[mt] visible".
// ---------------------------------------------------------------------------
__global__ __launch_bounds__(256, 1)
void k_lstm(const u16* __restrict__ X1, const u16* __restrict__ Whh,
            const u16* __restrict__ Wcf, const float* __restrict__ bc,
            const u16* __restrict__ Wfcb, const float* __restrict__ bfc,
            u16* __restrict__ hbuf, float* __restrict__ out,
            u32* __restrict__ flags)
{
  const int tid = threadIdx.x;
  const int w = tid >> 6, l = tid & 63;
  const int lr = l & 15, lg = l >> 4;
  const int bg = (int)blockIdx.x & 7, hg = (int)blockIdx.x >> 3;
  const int gt = lr >> 2;
  const int grow = gt * ZH + hg * 16 + w * 4 + (lr & 3);

  // persistent weights (compiler loads; dummy-consumed so waits land here)
  s8v bwh[16], bwx[4];
  {
    const u16* p = Whh + (size_t)grow * ZH + lg * 8;
    #pragma unroll
    for (int kt = 0; kt < 16; ++kt) bwh[kt] = *(const s8v*)(p + kt * 32);
    const u16* q = Wcf + (size_t)grow * ZEH + lg * 8;
    #pragma unroll
    for (int kt = 0; kt < 4; ++kt) bwx[kt] = *(const s8v*)(q + kt * 32);
  }
  float bias = bc[grow];
  #pragma unroll
  for (int kt = 0; kt < 16; ++kt) asm volatile("" :: "v"(bwh[kt]));
  #pragma unroll
  for (int kt = 0; kt < 4; ++kt) asm volatile("" :: "v"(bwx[kt]));
  asm volatile("" :: "v"(bias));
  f4v biasv = {bias, bias, bias, bias};

  float c_reg[4][4];
  #pragma unroll
  for (int a = 0; a < 4; ++a){
    #pragma unroll
    for (int b = 0; b < 4; ++b) c_reg[a][b] = 0.f;
  }

  const u64 hB  = (u64)(uintptr_t)hbuf;
  const u64 x1B = (u64)(uintptr_t)X1;
  const u64 fB  = (u64)(uintptr_t)flags + (u64)bg * 32768;
  const u64 fL  = fB + (u64)l * 64;              // lane-indexed (prefetch/poll)
  const u64 fS  = fB + (u64)(hg * 4 + w) * 64;   // self flag
  const u64 lane_off = (u64)((lg >> 1) * 512 + lr * 32 + (lg & 1) * 16);

  // h/x/flag double buffers (static-indexed via mt unroll)
  s8v avA[16], avB[16], xA[4], xB[4];
  u32 fpA0 = 0, fpA1 = 0, fpB0 = 0, fpB1 = 0;
  #pragma unroll
  for (int kt = 0; kt < 16; ++kt) avA[kt] = (s8v)(short)0;

  // preload X for slot (0,0) and drain everything
  {
    u64 xb_ = x1B + 2 * ((u64)(bg * 64 + 0 * 16 + lr) * ZEH + lg * 8);
    GLOAD4P(xA[0], xb_, 0); GLOAD4P(xA[1], xb_, 64);
    GLOAD4P(xA[2], xb_, 128); GLOAD4P(xA[3], xb_, 192);
  }
  WAITV(0);

#define SLOT_BODY(MT, AVU, AVF, XU, XF, FPU0, FPU1, FPF0, FPF1)                          \
  {                                                                                      \
    constexpr int mt1 = (MT + 1) & 3, mt2 = (MT + 2) & 3, mtp = (MT + 3) & 3;            \
    const int tq = t + (MT == 3);                                                        \
    WAITV(25);                                                                           \
    if (!(t == ZT - 1 && MT == 3)){                                                      \
      u64 ok = __ballot(FPU0 >= (u32)tq) & __ballot(FPU1 >= (u32)tq);                    \
      if (ok != ~0ull)                                                                   \
        pollwait(fL + ((u64)mt1 << 13), fL + ((u64)mt1 << 13) + 4096, (u32)tq);          \
      if (!(t == ZT - 1 && MT >= 2)){                                                    \
        u64 fa = fL + ((u64)mt2 << 13);                                                  \
        GLOADF(FPF0, fa); GLOADF(FPF1, fa + 4096);                                       \
      }                                                                                  \
      u64 qb0 = hB + qoffB(tq & 1, bg, mt1, 0) + lane_off;                               \
      u64 qb1 = qb0 + 4096, qb2 = qb0 + 8192, qb3 = qb0 + 12288;                         \
      GLOAD4S(AVF[0],  qb0, 0); GLOAD4S(AVF[1],  qb0, 1024);                             \
      GLOAD4S(AVF[2],  qb0, 2048); GLOAD4S(AVF[3],  qb0, 3072);                          \
      GLOAD4S(AVF[4],  qb1, 0); GLOAD4S(AVF[5],  qb1, 1024);                             \
      GLOAD4S(AVF[6],  qb1, 2048); GLOAD4S(AVF[7],  qb1, 3072);                          \
      GLOAD4S(AVF[8],  qb2, 0); GLOAD4S(AVF[9],  qb2, 1024);                             \
      GLOAD4S(AVF[10], qb2, 2048); GLOAD4S(AVF[11], qb2, 3072);                          \
      GLOAD4S(AVF[12], qb3, 0); GLOAD4S(AVF[13], qb3, 1024);                             \
      GLOAD4S(AVF[14], qb3, 2048); GLOAD4S(AVF[15], qb3, 3072);                          \
      u64 xb_ = x1B + 2 * (((u64)tq * ZB + bg * 64 + mt1 * 16 + lr) * ZEH + lg * 8);     \
      GLOAD4P(XF[0], xb_, 0); GLOAD4P(XF[1], xb_, 64);                                   \
      GLOAD4P(XF[2], xb_, 128); GLOAD4P(XF[3], xb_, 192);                                \
    }                                                                                    \
    WAITV(27);                                                                           \
    f4v a0 = biasv, a1 = {0.f, 0.f, 0.f, 0.f};                                           \
    a0 = __builtin_amdgcn_mfma_f32_16x16x32_bf16(AVU[0],  bwh[0],  a0, 0, 0, 0);         \
    a0 = __builtin_amdgcn_mfma_f32_16x16x32_bf16(AVU[1],  bwh[1],  a0, 0, 0, 0);         \
    a0 = __builtin_amdgcn_mfma_f32_16x16x32_bf16(AVU[2],  bwh[2],  a0, 0, 0, 0);         \
    a0 = __builtin_amdgcn_mfma_f32_16x16x32_bf16(AVU[3],  bwh[3],  a0, 0, 0, 0);         \
    a0 = __builtin_amdgcn_mfma_f32_16x16x32_bf16(AVU[4],  bwh[4],  a0, 0, 0, 0);         \
    a0 = __builtin_amdgcn_mfma_f32_16x16x32_bf16(AVU[5],  bwh[5],  a0, 0, 0, 0);         \
    a0 = __builtin_amdgcn_mfma_f32_16x16x32_bf16(AVU[6],  bwh[6],  a0, 0, 0, 0);         \
    a0 = __builtin_amdgcn_mfma_f32_16x16x32_bf16(AVU[7],  bwh[7],  a0, 0, 0, 0);         \
    a1 = __builtin_amdgcn_mfma_f32_16x16x32_bf16(AVU[8],  bwh[8],  a1, 0, 0, 0);         \
    a1 = __builtin_amdgcn_mfma_f32_16x16x32_bf16(AVU[9],  bwh[9],  a1, 0, 0, 0);         \
    a1 = __builtin_amdgcn_mfma_f32_16x16x32_bf16(AVU[10], bwh[10], a1, 0, 0, 0);         \
    a1 = __builtin_amdgcn_mfma_f32_16x16x32_bf16(AVU[11], bwh[11], a1, 0, 0, 0);         \
    a1 = __builtin_amdgcn_mfma_f32_16x16x32_bf16(AVU[12], bwh[12], a1, 0, 0, 0);         \
    a1 = __builtin_amdgcn_mfma_f32_16x16x32_bf16(AVU[13], bwh[13], a1, 0, 0, 0);         \
    a1 = __builtin_amdgcn_mfma_f32_16x16x32_bf16(AVU[14], bwh[14], a1, 0, 0, 0);         \
    a1 = __builtin_amdgcn_mfma_f32_16x16x32_bf16(AVU[15], bwh[15], a1, 0, 0, 0);         \
    a0 = __builtin_amdgcn_mfma_f32_16x16x32_bf16(XU[0], bwx[0], a0, 0, 0, 0);            \
    a1 = __builtin_amdgcn_mfma_f32_16x16x32_bf16(XU[1], bwx[1], a1, 0, 0, 0);            \
    a0 = __builtin_amdgcn_mfma_f32_16x16x32_bf16(XU[2], bwx[2], a0, 0, 0, 0);            \
    a1 = __builtin_amdgcn_mfma_f32_16x16x32_bf16(XU[3], bwx[3], a1, 0, 0, 0);            \
    f4v acc = a0 + a1;                                                                   \
    u64 pk0, pk1, pk2, pk3;                                                              \
    _Pragma("unroll")                                                                    \
    for (int r = 0; r < 4; ++r){                                                         \
      float v = acc[r];                                                                  \
      float s = (gt == 2) ? 2.f : -1.f;                                                  \
      float e = __expf(v * s);                                                           \
      float rc = 1.f / (1.f + e);                                                        \
      float a = (gt == 2) ? (1.f - 2.f * rc) : rc;                                       \
      float f_ = __shfl_xor(a, 4);                                                       \
      float g_ = __shfl_xor(a, 8);                                                       \
      float o_ = __shfl_xor(a, 12);                                                      \
      float cv = f_ * c_reg[MT][r] + a * g_;                                             \
      c_reg[MT][r] = cv;                                                                 \
      float e2 = __expf(2.f * cv);                                                       \
      float hv = o_ * (1.f - 2.f / (1.f + e2));                                          \
      u32 bits = f2bf(hv);                                                               \
      u32 lo = bits | (((u32)__shfl_xor((int)bits, 1)) << 16);                           \
      u32 hi = (u32)__shfl_xor((int)lo, 2);                                              \
      u64 pk = (u64)lo | ((u64)hi << 32);                                                \
      if (r == 0) pk0 = pk; else if (r == 1) pk1 = pk;                                   \
      else if (r == 2) pk2 = pk; else pk3 = pk;                                          \
    }                                                                                    \
    u64 sb = hB + qoffB((t + 1) & 1, bg, MT, hg) + (u64)(lg * 128 + w * 8);              \
    if (lr == 0){                                                                        \
      GSTORE2S(sb, pk0, 0);  GSTORE2S(sb, pk1, 32);                                      \
      GSTORE2S(sb, pk2, 64); GSTORE2S(sb, pk3, 96);                                      \
    }                                                                                    \
    if (t == ZT - 1 && MT >= 2){ WAITV(0); } else { WAITV(27); }                         \
    if (MT > 0 || t > 0){                                                                \
      u32 fv = (MT == 0) ? (u32)t : (u32)(t + 1);                                        \
      if (l == 0) GSTOREF(fS + ((u64)mtp << 13), fv);                                    \
    }                                                                                    \
  }

  for (int t = 0; t < ZT; ++t){
    SLOT_BODY(0, avA, avB, xA, xB, fpA0, fpA1, fpB0, fpB1)
    SLOT_BODY(1, avB, avA, xB, xA, fpB0, fpB1, fpA0, fpA1)
    SLOT_BODY(2, avA, avB, xA, xB, fpA0, fpA1, fpB0, fpB1)
    SLOT_BODY(3, avB, avA, xB, xA, fpB0, fpB1, fpA0, fpA1)
  }
#undef SLOT_BODY

  // final ack + flag for quarter (255,3)
  WAITV(0);
  if (l == 0) GSTOREF(fS + ((u64)3 << 13), (u32)ZT);

  // epilogue: hg==0 waves compute out = h_256 @ Wfc^T + bfc (h_256 in buf 0)
  if (hg == 0){
    #pragma unroll
    for (int mt = 0; mt < 4; ++mt)
      pollwait(fL + ((u64)mt << 13), fL + ((u64)mt << 13) + 4096, (u32)ZT);
    float ob = (lr < ZNC) ? bfc[lr] : 0.f;
    f4v acc = {ob, ob, ob, ob};
    const u16* wp = Wfcb + (size_t)lr * ZH + lg * 8;
    #pragma unroll
    for (int kt = 0; kt < 16; ++kt){
      int hgp = 2 * kt + (lg >> 1);
      const u64* hp = (const u64*)((const char*)hbuf + qoffB(0, bg, w, hgp));
      u64 a0 = aload(hp + lr * 4 + (lg & 1) * 2);
      u64 a1 = aload(hp + lr * 4 + (lg & 1) * 2 + 1);
      s8v av = pair2v(a0, a1);
      s8v bv = *(const s8v*)(wp + kt * 32);
      acc = __builtin_amdgcn_mfma_f32_16x16x32_bf16(av, bv, acc, 0, 0, 0);
    }
    if (lr < ZNC){
      #pragma unroll
      for (int r = 0; r < 4; ++r)
        out[(size_t)(bg * 64 + w * 16 + lg * 4 + r) * ZNC + lr] = acc[r];
    }
  }
}

// ---------------------------------------------------------------------------
extern "C" void kernel_launch(void* const* d_in, const int* in_sizes, int n_in,
                              void* d_out, int out_size, void* d_ws, size_t ws_size,
                              hipStream_t stream)
{
  const float* seq  = (const float*)d_in[0];
  const float* W1   = (const float*)d_in[1];
  const float* b1   = (const float*)d_in[2];
  const float* W2   = (const float*)d_in[3];
  const float* b2   = (const float*)d_in[4];
  const float* W_ih = (const float*)d_in[5];
  const float* W_hh = (const float*)d_in[6];
  const float* b_ih = (const float*)d_in[7];
  const float* b_hh = (const float*)d_in[8];
  const float* Wfc  = (const float*)d_in[9];
  const float* bfc  = (const float*)d_in[10];
  float* out = (float*)d_out;

  char* ws = (char*)d_ws;
  size_t off = 0;
  auto alloc = [&](size_t bytes){ void* p = ws + off; off += (bytes + 255) & ~(size_t)255; return p; };
  u16*   Wc    = (u16*)  alloc((size_t)ZG * ZEH * 2);
  float* bc    = (float*)alloc((size_t)ZG * 4);
  u16*   Whh   = (u16*)  alloc((size_t)ZG * ZH * 2);
  u16*   Wfcb  = (u16*)  alloc((size_t)16 * ZH * 2);
  u16*   X1    = (u16*)  alloc((size_t)ZB * ZT * ZEH * 2);
  u16*   hbuf  = (u16*)  alloc((size_t)2 * ZB * ZH * 2);
  u32*   flags = (u32*)  alloc((size_t)8 * 4 * 128 * 64);   // 64B-padded per (bg,mt,hg,w)

  hipMemsetAsync(flags, 0, (size_t)8 * 4 * 128 * 64, stream);
  hipMemsetAsync(hbuf, 0, (size_t)ZB * ZH * 2, stream);      // h_0 = 0 (buffer 0)
  hipMemsetAsync(Wfcb, 0, (size_t)16 * ZH * 2, stream);      // pad rows 8..15 = 0

  hipLaunchKernelGGL(k_fold, dim3(ZG), dim3(128), 0, stream, W_ih, W2, b2, b_ih, b_hh, Wc, bc);
  hipLaunchKernelGGL(k_cvt, dim3((ZG * ZH + 255) / 256), dim3(256), 0, stream, W_hh, Whh, ZG * ZH);
  hipLaunchKernelGGL(k_cvt, dim3((ZNC * ZH + 255) / 256), dim3(256), 0, stream, Wfc, Wfcb, ZNC * ZH);
  hipLaunchKernelGGL(k_enc, dim3(ZB * ZT / 64), dim3(256), 0, stream, seq, W1, b1, X1);
  hipLaunchKernelGGL(k_lstm, dim3(256), dim3(256), 0, stream,
                     X1, Whh, Wc, bc, Wfcb, bfc, hbuf, out, flags);
}

// Round 11
// 2588.974 us; speedup vs baseline: 1.2447x; 1.2447x over previous
//
#include <hip/hip_runtime.h>
#include <cstdint>
#include <cstddef>

#define ZB 512
#define ZT 256
#define ZIN 64
#define ZEH 128
#define ZH 512
#define ZG 2048
#define ZNC 8
#define NBLK 256

typedef __attribute__((ext_vector_type(8))) short s8v;
typedef __attribute__((ext_vector_type(4))) float f4v;
typedef unsigned short u16;
typedef unsigned int u32;
typedef unsigned long long u64;

__device__ __forceinline__ u16 f2bf(float f){
  u32 u = __builtin_bit_cast(u32, f);
  u += 0x7FFFu + ((u >> 16) & 1u);
  return (u16)(u >> 16);
}
__device__ __forceinline__ s8v pair2v(u64 a, u64 b){
  union { u64 q[2]; s8v v; } u; u.q[0] = a; u.q[1] = b; return u.v;
}
// h layout: [buf][bg][mt][hg][16 rows][16 cols] u16; chunk = 512B contiguous
__device__ __forceinline__ size_t qoff(int buf, int bg, int mt, int hg){
  return ((((size_t)buf * 8 + bg) * 4 + mt) * 32 + hg) * 256;
}
__device__ __forceinline__ u64 aload(const u64* p){
  return __hip_atomic_load(p, __ATOMIC_RELAXED, __HIP_MEMORY_SCOPE_AGENT);
}

// ---------------------------------------------------------------------------
// Fold: Wc[2048][128] = W_ih @ W2 (bf16), bc[2048] = W_ih@b2 + b_ih + b_hh
// ---------------------------------------------------------------------------
__global__ __launch_bounds__(128)
void k_fold(const float* __restrict__ W_ih, const float* __restrict__ W2,
            const float* __restrict__ b2, const float* __restrict__ b_ih,
            const float* __restrict__ b_hh, u16* __restrict__ Wc,
            float* __restrict__ bc)
{
  const int r = blockIdx.x, c = threadIdx.x;
  const float* wr = W_ih + (size_t)r * ZH;
  float acc = 0.f;
  for (int k = 0; k < ZH; ++k) acc += wr[k] * W2[(size_t)k * ZEH + c];
  Wc[(size_t)r * ZEH + c] = f2bf(acc);
  __shared__ float red[128];
  float p = 0.f;
  for (int k = c; k < ZH; k += 128) p += wr[k] * b2[k];
  red[c] = p; __syncthreads();
  for (int s = 64; s > 0; s >>= 1){ if (c < s) red[c] += red[c + s]; __syncthreads(); }
  if (c == 0) bc[r] = red[0] + b_ih[r] + b_hh[r];
}

// ---------------------------------------------------------------------------
// f32 -> bf16 cast
// ---------------------------------------------------------------------------
__global__ __launch_bounds__(256)
void k_cvt(const float* __restrict__ src, u16* __restrict__ dst, int n)
{
  int i = blockIdx.x * 256 + threadIdx.x;
  if (i < n) dst[i] = f2bf(src[i]);
}

// ---------------------------------------------------------------------------
// Encoder layer 1: X1 (t-major: [T][B][128]) = bf16(LeakyReLU(seq@W1^T+b1))
// ---------------------------------------------------------------------------
__global__ __launch_bounds__(256)
void k_enc(const float* __restrict__ seq, const float* __restrict__ W1,
           const float* __restrict__ b1, u16* __restrict__ X1)
{
  __shared__ float w1s[ZEH * 65];
  __shared__ float sqs[64 * 65];
  const int tid = threadIdx.x;
  const size_t rb = (size_t)blockIdx.x * 64;
  for (int i = tid; i < ZEH * ZIN; i += 256){ int r = i >> 6, c = i & 63; w1s[r * 65 + c] = W1[i]; }
  for (int i = tid; i < 64 * ZIN; i += 256){ int r = i >> 6, c = i & 63; sqs[r * 65 + c] = seq[(rb + r) * ZIN + c]; }
  __syncthreads();
  const int cg = tid & 31, rg = tid >> 5;
  float acc[8][4];
  #pragma unroll
  for (int i = 0; i < 8; ++i){
    #pragma unroll
    for (int j = 0; j < 4; ++j) acc[i][j] = 0.f;
  }
  for (int k = 0; k < ZIN; ++k){
    float wv[4], sv[8];
    #pragma unroll
    for (int j = 0; j < 4; ++j) wv[j] = w1s[(cg * 4 + j) * 65 + k];
    #pragma unroll
    for (int i = 0; i < 8; ++i) sv[i] = sqs[(rg * 8 + i) * 65 + k];
    #pragma unroll
    for (int i = 0; i < 8; ++i){
      #pragma unroll
      for (int j = 0; j < 4; ++j) acc[i][j] += sv[i] * wv[j];
    }
  }
  #pragma unroll
  for (int i = 0; i < 8; ++i){
    ushort4 pk;
    float v0 = acc[i][0] + b1[cg * 4 + 0]; v0 = v0 > 0.f ? v0 : 0.01f * v0;
    float v1 = acc[i][1] + b1[cg * 4 + 1]; v1 = v1 > 0.f ? v1 : 0.01f * v1;
    float v2 = acc[i][2] + b1[cg * 4 + 2]; v2 = v2 > 0.f ? v2 : 0.01f * v2;
    float v3 = acc[i][3] + b1[cg * 4 + 3]; v3 = v3 > 0.f ? v3 : 0.01f * v3;
    pk.x = f2bf(v0); pk.y = f2bf(v1); pk.z = f2bf(v2); pk.w = f2bf(v3);
    int rf = (int)rb + rg * 8 + i;            // flat b*T + t
    int b = rf >> 8, tt = rf & 255;
    *(ushort4*)(X1 + ((size_t)tt * ZB + b) * ZEH + cg * 4) = pk;
  }
}

// ---------------------------------------------------------------------------
// quarter wait: lane l polls flag[bg][mt][l&31] (agent scope / MALL).
// ---------------------------------------------------------------------------
__device__ __forceinline__ void qwait(const u32* flags, int bg, int mt, u32 target)
{
  const int l = threadIdx.x & 63;
  const u32* fp = flags + ((size_t)((bg * 4 + mt) * 32 + (l & 31))) * 16;
  long long guard = 0;
  for (;;){
    u32 v = __hip_atomic_load(fp, __ATOMIC_RELAXED, __HIP_MEMORY_SCOPE_AGENT);
    if (__ballot(v >= target) == ~0ull) break;
    __builtin_amdgcn_s_sleep(1);
    if (++guard > (1LL << 20)) break;   // fail loud (wrong answer), never hang
  }
}

// ---------------------------------------------------------------------------
// Cooperative LSTM, wave-specialized (round-6 structure + raw barriers).
// 256 blocks = 8 bg x 32 hg, 512 thr:
//   waves 0-3 compute: W_hh/Wc slices in regs, MFMA + cell + h agent-stores.
//     At TOP of each slot: vmcnt(0) (stores from the PREVIOUS slot, a full
//     slot old -> nearly-free ack) then publish that quarter's flag.
//   waves 4-7 stage: commit bank fetched 1 slot ago into the idle LDS half,
//     ballot-check prefetched flags (qwait poll on miss), issue MALL fetch
//     for slot+2 and flag prefetch for slot+3. With RAW barriers the fetch
//     latency spans slots via the compiler's own dependency-placed vmcnt.
// Slot end = lgkmcnt(0) + s_barrier + sched_barrier (NO vmcnt drain).
// ---------------------------------------------------------------------------
__global__ __launch_bounds__(512, 1)
void k_lstm(const u16* __restrict__ X1, const u16* __restrict__ Whh,
            const u16* __restrict__ Wcf, const float* __restrict__ bc,
            const u16* __restrict__ Wfcb, const float* __restrict__ bfc,
            u16* __restrict__ hbuf, float* __restrict__ out,
            u32* __restrict__ flags)
{
  __shared__ u16 hs2[2][16 * ZH];   // 2 x 16 KiB, XOR-swizzled quarter tiles
  const int tid = threadIdx.x;
  const int bg = (int)blockIdx.x >> 5, hg = (int)blockIdx.x & 31;
  const bool isC = (tid < 256);
  const int w = (tid >> 6) & 3, l = tid & 63;
  const int lr = l & 15, lg = l >> 4;
  const int st = tid & 255;
  const int gt = lr >> 2;

  // ---- compute-role persistent state ----
  s8v bwh[16], bwx[4];
  f4v biasv = {0.f, 0.f, 0.f, 0.f};
  float c_reg[4][4];
  if (isC){
    const int grow = gt * ZH + hg * 16 + w * 4 + (lr & 3);
    const u16* p = Whh + (size_t)grow * ZH + lg * 8;
    #pragma unroll
    for (int kt = 0; kt < 16; ++kt) bwh[kt] = *(const s8v*)(p + kt * 32);
    const u16* q = Wcf + (size_t)grow * ZEH + lg * 8;
    #pragma unroll
    for (int kt = 0; kt < 4; ++kt) bwx[kt] = *(const s8v*)(q + kt * 32);
    float b = bc[grow];
    biasv[0] = b; biasv[1] = b; biasv[2] = b; biasv[3] = b;
    #pragma unroll
    for (int a = 0; a < 4; ++a){
      #pragma unroll
      for (int bq = 0; bq < 4; ++bq) c_reg[a][bq] = 0.f;
    }
  }

  // ---- stage-role prologue: bank E = quarter (0,0) (committed to hs2[0]),
  //      bank O = quarter (0,1) held in registers ----
  u64 vaE[4], vbE[4], vaO[4], vbO[4];
  if (!isC){
    const u64* s0 = (const u64*)(hbuf + qoff(0, bg, 0, 0));
    const u64* s1 = (const u64*)(hbuf + qoff(0, bg, 1, 0));
    #pragma unroll
    for (int i = 0; i < 4; ++i){
      int cc = st + i * 256;
      vaE[i] = aload(s0 + (size_t)cc * 2); vbE[i] = aload(s0 + (size_t)cc * 2 + 1);
      vaO[i] = aload(s1 + (size_t)cc * 2); vbO[i] = aload(s1 + (size_t)cc * 2 + 1);
    }
    #pragma unroll
    for (int i = 0; i < 4; ++i){
      int byte = (st + i * 256) * 16;
      int swz = byte ^ (((byte >> 5) & 3) << 4);
      *(s8v*)((char*)hs2[0] + swz) = pair2v(vaE[i], vbE[i]);
    }
  }
  u32 fpre = 0;
  __syncthreads();

  u32* fl0 = flags + ((size_t)(bg * 4 * 32 + hg)) * 16;

  for (int t = 0; t < ZT; ++t){
    #pragma unroll
    for (int mt = 0; mt < 4; ++mt){
      if (isC){
        // ack stores of the PREVIOUS slot (a full slot old -> cheap) and
        // publish its quarter flag; release order: drain precedes flag.
        if (!(t == 0 && mt == 0)){
          asm volatile("s_waitcnt vmcnt(0)" ::: "memory");
          __builtin_amdgcn_sched_barrier(0);
          if (tid == 0){
            const int pmt = (mt + 3) & 3;
            const u32 fv = (mt == 0) ? (u32)t : (u32)(t + 1);
            __hip_atomic_store(fl0 + (size_t)pmt * 512, fv,
                               __ATOMIC_RELAXED, __HIP_MEMORY_SCOPE_AGENT);
          }
        }

        // X fragments for THIS slot (t-major layout; latency under h-chain)
        const u16* xp = X1 + ((size_t)t * ZB + (bg * 64 + mt * 16 + lr)) * ZEH + lg * 8;
        s8v ax0 = *(const s8v*)(xp);
        s8v ax1 = *(const s8v*)(xp + 32);
        s8v ax2 = *(const s8v*)(xp + 64);
        s8v ax3 = *(const s8v*)(xp + 96);

        // two independent MFMA chains over the h tile
        f4v a0 = biasv;
        f4v a1 = {0.f, 0.f, 0.f, 0.f};
        const char* hb = (const char*)hs2[mt & 1];
        #pragma unroll
        for (int kt = 0; kt < 8; ++kt){
          int byte = (2 * kt + (lg >> 1)) * 512 + lr * 32 + (lg & 1) * 16;
          byte ^= ((lr & 3) << 4);
          s8v av = *(const s8v*)(hb + byte);
          a0 = __builtin_amdgcn_mfma_f32_16x16x32_bf16(av, bwh[kt], a0, 0, 0, 0);
        }
        #pragma unroll
        for (int kt = 8; kt < 16; ++kt){
          int byte = (2 * kt + (lg >> 1)) * 512 + lr * 32 + (lg & 1) * 16;
          byte ^= ((lr & 3) << 4);
          s8v av = *(const s8v*)(hb + byte);
          a1 = __builtin_amdgcn_mfma_f32_16x16x32_bf16(av, bwh[kt], a1, 0, 0, 0);
        }
        a0 = __builtin_amdgcn_mfma_f32_16x16x32_bf16(ax0, bwx[0], a0, 0, 0, 0);
        a1 = __builtin_amdgcn_mfma_f32_16x16x32_bf16(ax1, bwx[1], a1, 0, 0, 0);
        a0 = __builtin_amdgcn_mfma_f32_16x16x32_bf16(ax2, bwx[2], a0, 0, 0, 0);
        a1 = __builtin_amdgcn_mfma_f32_16x16x32_bf16(ax3, bwx[3], a1, 0, 0, 0);
        f4v acc = a0 + a1;

        // LSTM cell; gather f,g,o across gate lanes (stride 4); h -> global
        u16* hdst = hbuf + qoff((t + 1) & 1, bg, mt, hg);
        #pragma unroll
        for (int r = 0; r < 4; ++r){
          float v = acc[r];
          float s = (gt == 2) ? 2.f : -1.f;
          float e = __expf(v * s);
          float rc = 1.f / (1.f + e);
          float a = (gt == 2) ? (1.f - 2.f * rc) : rc;   // tanh : sigmoid
          float f_ = __shfl_xor(a, 4);
          float g_ = __shfl_xor(a, 8);
          float o_ = __shfl_xor(a, 12);
          float cv = f_ * c_reg[mt][r] + a * g_;
          c_reg[mt][r] = cv;
          float e2 = __expf(2.f * cv);
          float hv = o_ * (1.f - 2.f / (1.f + e2));
          u32 bits = f2bf(hv);
          u32 lo = bits | (((u32)__shfl_xor((int)bits, 1)) << 16);
          u32 hi = (u32)__shfl_xor((int)lo, 2);
          if (lr == 0){
            u64 pk = (u64)lo | ((u64)hi << 32);
            __hip_atomic_store((u64*)(hdst + (size_t)(lg * 4 + r) * 16 + w * 4), pk,
                               __ATOMIC_RELAXED, __HIP_MEMORY_SCOPE_AGENT);
          }
        }
        // NO vmcnt drain here: ack happens at the top of the next slot.
      } else {
        // 1) commit registers fetched 1 slot ago -> hs2[(mt+1)&1]
        //    (compiler inserts its own vmcnt wait before these uses,
        //     letting the fetch latency span the raw slot barrier)
        if (!(t == ZT - 1 && mt == 3)){
          char* dst = (char*)hs2[(mt + 1) & 1];
          if ((mt & 1) == 0){
            #pragma unroll
            for (int i = 0; i < 4; ++i){
              int byte = (st + i * 256) * 16;
              int swz = byte ^ (((byte >> 5) & 3) << 4);
              *(s8v*)(dst + swz) = pair2v(vaO[i], vbO[i]);
            }
          } else {
            #pragma unroll
            for (int i = 0; i < 4; ++i){
              int byte = (st + i * 256) * 16;
              int swz = byte ^ (((byte >> 5) & 3) << 4);
              *(s8v*)(dst + swz) = pair2v(vaE[i], vbE[i]);
            }
          }
        }
        // 2) fetch quarter for slot+2 (check prefetched flag; poll on miss)
        {
          const int tc = t + (mt >> 1);
          const int mtc = (mt + 2) & 3;
          if (tc < ZT){
            if (__ballot(fpre >= (u32)tc) != ~0ull) qwait(flags, bg, mtc, (u32)tc);
            const u64* src = (const u64*)(hbuf + qoff(tc & 1, bg, mtc, 0));
            if ((mt & 1) == 0){
              #pragma unroll
              for (int i = 0; i < 4; ++i){
                int cc = st + i * 256;
                vaE[i] = aload(src + (size_t)cc * 2);
                vbE[i] = aload(src + (size_t)cc * 2 + 1);
              }
            } else {
              #pragma unroll
              for (int i = 0; i < 4; ++i){
                int cc = st + i * 256;
                vaO[i] = aload(src + (size_t)cc * 2);
                vbO[i] = aload(src + (size_t)cc * 2 + 1);
              }
            }
          }
        }
        // 3) prefetch flag for the check at slot+1
        {
          const int tn = t + ((mt + 3) >> 2);
          const int mtn = (mt + 3) & 3;
          if (tn < ZT)
            fpre = __hip_atomic_load(flags + ((size_t)((bg * 4 + mtn) * 32 + (l & 31))) * 16,
                                     __ATOMIC_RELAXED, __HIP_MEMORY_SCOPE_AGENT);
        }
      }
      // slot end: order LDS writes, raw barrier (no vmcnt drain), pin order
      asm volatile("s_waitcnt lgkmcnt(0)" ::: "memory");
      __builtin_amdgcn_s_barrier();
      __builtin_amdgcn_sched_barrier(0);
    }
  }

  // final: ack last slot's stores, publish quarter (255,3)
  if (isC){
    asm volatile("s_waitcnt vmcnt(0)" ::: "memory");
    if (tid == 0)
      __hip_atomic_store(fl0 + (size_t)3 * 512, (u32)ZT,
                         __ATOMIC_RELAXED, __HIP_MEMORY_SCOPE_AGENT);
  }

  // epilogue: hg==0 blocks compute out = h_T @ Wfc^T + bfc (h_T in buf 0)
  if (hg == 0){
    if (tid < 64){
      #pragma unroll
      for (int mt = 0; mt < 4; ++mt) qwait(flags, bg, mt, (u32)ZT);
    }
    __syncthreads();
    if (isC){
      float ob = (lr < ZNC) ? bfc[lr] : 0.f;
      f4v acc = {ob, ob, ob, ob};
      const u16* wp = Wfcb + (size_t)lr * ZH + lg * 8;
      #pragma unroll
      for (int kt = 0; kt < 16; ++kt){
        int hgp = 2 * kt + (lg >> 1);
        const u64* hp = (const u64*)(hbuf + qoff(0, bg, w, hgp));
        u64 a0 = aload(hp + lr * 4 + (lg & 1) * 2);
        u64 a1 = aload(hp + lr * 4 + (lg & 1) * 2 + 1);
        s8v av = pair2v(a0, a1);
        s8v bv = *(const s8v*)(wp + kt * 32);
        acc = __builtin_amdgcn_mfma_f32_16x16x32_bf16(av, bv, acc, 0, 0, 0);
      }
      if (lr < ZNC){
        #pragma unroll
        for (int r = 0; r < 4; ++r)
          out[(size_t)(bg * 64 + w * 16 + lg * 4 + r) * ZNC + lr] = acc[r];
      }
    }
  }
}

// ---------------------------------------------------------------------------
extern "C" void kernel_launch(void* const* d_in, const int* in_sizes, int n_in,
                              void* d_out, int out_size, void* d_ws, size_t ws_size,
                              hipStream_t stream)
{
  const float* seq  = (const float*)d_in[0];
  const float* W1   = (const float*)d_in[1];
  const float* b1   = (const float*)d_in[2];
  const float* W2   = (const float*)d_in[3];
  const float* b2   = (const float*)d_in[4];
  const float* W_ih = (const float*)d_in[5];
  const float* W_hh = (const float*)d_in[6];
  const float* b_ih = (const float*)d_in[7];
  const float* b_hh = (const float*)d_in[8];
  const float* Wfc  = (const float*)d_in[9];
  const float* bfc  = (const float*)d_in[10];
  float* out = (float*)d_out;

  char* ws = (char*)d_ws;
  size_t off = 0;
  auto alloc = [&](size_t bytes){ void* p = ws + off; off += (bytes + 255) & ~(size_t)255; return p; };
  u16*   Wc    = (u16*)  alloc((size_t)ZG * ZEH * 2);
  float* bc    = (float*)alloc((size_t)ZG * 4);
  u16*   Whh   = (u16*)  alloc((size_t)ZG * ZH * 2);
  u16*   Wfcb  = (u16*)  alloc((size_t)16 * ZH * 2);
  u16*   X1    = (u16*)  alloc((size_t)ZB * ZT * ZEH * 2);
  u16*   hbuf  = (u16*)  alloc((size_t)2 * ZB * ZH * 2);
  u32*   flags = (u32*)  alloc((size_t)8 * 4 * 32 * 16 * 4);  // 64B-padded per (bg,mt,hg)

  hipMemsetAsync(flags, 0, (size_t)8 * 4 * 32 * 16 * 4, stream);
  hipMemsetAsync(hbuf, 0, (size_t)ZB * ZH * 2, stream);      // h_0 = 0 (buffer 0)
  hipMemsetAsync(Wfcb, 0, (size_t)16 * ZH * 2, stream);      // pad rows 8..15 = 0

  hipLaunchKernelGGL(k_fold, dim3(ZG), dim3(128), 0, stream, W_ih, W2, b2, b_ih, b_hh, Wc, bc);
  hipLaunchKernelGGL(k_cvt, dim3((ZG * ZH + 255) / 256), dim3(256), 0, stream, W_hh, Whh, ZG * ZH);
  hipLaunchKernelGGL(k_cvt, dim3((ZNC * ZH + 255) / 256), dim3(256), 0, stream, Wfc, Wfcb, ZNC * ZH);
  hipLaunchKernelGGL(k_enc, dim3(ZB * ZT / 64), dim3(256), 0, stream, seq, W1, b1, X1);
  hipLaunchKernelGGL(k_lstm, dim3(NBLK), dim3(512), 0, stream,
                     X1, Whh, Wc, bc, Wfcb, bfc, hbuf, out, flags);
}

// Round 12
// 1758.940 us; speedup vs baseline: 1.8320x; 1.4719x over previous
//
#include <hip/hip_runtime.h>
#include <cstdint>
#include <cstddef>

#define ZB 512
#define ZT 256
#define ZIN 64
#define ZEH 128
#define ZH 512
#define ZG 2048
#define ZNC 8
#define NBLK 256

typedef __attribute__((ext_vector_type(8))) short s8v;
typedef __attribute__((ext_vector_type(4))) float f4v;
typedef unsigned short u16;
typedef unsigned int u32;
typedef unsigned long long u64;

__device__ __forceinline__ u16 f2bf(float f){
  u32 u = __builtin_bit_cast(u32, f);
  u += 0x7FFFu + ((u >> 16) & 1u);
  return (u16)(u >> 16);
}
__device__ __forceinline__ s8v pair2v(u64 a, u64 b){
  union { u64 q[2]; s8v v; } u; u.q[0] = a; u.q[1] = b; return u.v;
}
// h layout: [buf2][bg8][half2][hg32][32 rows][16 cols] u16; chunk = 1KB/hg
__device__ __forceinline__ size_t qoff2(int buf, int bg, int hf, int hg){
  return ((((size_t)buf * 8 + bg) * 2 + hf) * 32 + hg) * 512;   // u16 elements
}
__device__ __forceinline__ u64 aload(const u64* p){
  return __hip_atomic_load(p, __ATOMIC_RELAXED, __HIP_MEMORY_SCOPE_AGENT);
}

// ---------------------------------------------------------------------------
// Fold: Wc[2048][128] = W_ih @ W2 (bf16), bc[2048] = W_ih@b2 + b_ih + b_hh
// ---------------------------------------------------------------------------
__global__ __launch_bounds__(128)
void k_fold(const float* __restrict__ W_ih, const float* __restrict__ W2,
            const float* __restrict__ b2, const float* __restrict__ b_ih,
            const float* __restrict__ b_hh, u16* __restrict__ Wc,
            float* __restrict__ bc)
{
  const int r = blockIdx.x, c = threadIdx.x;
  const float* wr = W_ih + (size_t)r * ZH;
  float acc = 0.f;
  for (int k = 0; k < ZH; ++k) acc += wr[k] * W2[(size_t)k * ZEH + c];
  Wc[(size_t)r * ZEH + c] = f2bf(acc);
  __shared__ float red[128];
  float p = 0.f;
  for (int k = c; k < ZH; k += 128) p += wr[k] * b2[k];
  red[c] = p; __syncthreads();
  for (int s = 64; s > 0; s >>= 1){ if (c < s) red[c] += red[c + s]; __syncthreads(); }
  if (c == 0) bc[r] = red[0] + b_ih[r] + b_hh[r];
}

__global__ __launch_bounds__(256)
void k_cvt(const float* __restrict__ src, u16* __restrict__ dst, int n)
{
  int i = blockIdx.x * 256 + threadIdx.x;
  if (i < n) dst[i] = f2bf(src[i]);
}

// ---------------------------------------------------------------------------
// Encoder layer 1: X1 (t-major: [T][B][128]) = bf16(LeakyReLU(seq@W1^T+b1))
// ---------------------------------------------------------------------------
__global__ __launch_bounds__(256)
void k_enc(const float* __restrict__ seq, const float* __restrict__ W1,
           const float* __restrict__ b1, u16* __restrict__ X1)
{
  __shared__ float w1s[ZEH * 65];
  __shared__ float sqs[64 * 65];
  const int tid = threadIdx.x;
  const size_t rb = (size_t)blockIdx.x * 64;
  for (int i = tid; i < ZEH * ZIN; i += 256){ int r = i >> 6, c = i & 63; w1s[r * 65 + c] = W1[i]; }
  for (int i = tid; i < 64 * ZIN; i += 256){ int r = i >> 6, c = i & 63; sqs[r * 65 + c] = seq[(rb + r) * ZIN + c]; }
  __syncthreads();
  const int cg = tid & 31, rg = tid >> 5;
  float acc[8][4];
  #pragma unroll
  for (int i = 0; i < 8; ++i){
    #pragma unroll
    for (int j = 0; j < 4; ++j) acc[i][j] = 0.f;
  }
  for (int k = 0; k < ZIN; ++k){
    float wv[4], sv[8];
    #pragma unroll
    for (int j = 0; j < 4; ++j) wv[j] = w1s[(cg * 4 + j) * 65 + k];
    #pragma unroll
    for (int i = 0; i < 8; ++i) sv[i] = sqs[(rg * 8 + i) * 65 + k];
    #pragma unroll
    for (int i = 0; i < 8; ++i){
      #pragma unroll
      for (int j = 0; j < 4; ++j) acc[i][j] += sv[i] * wv[j];
    }
  }
  #pragma unroll
  for (int i = 0; i < 8; ++i){
    ushort4 pk;
    float v0 = acc[i][0] + b1[cg * 4 + 0]; v0 = v0 > 0.f ? v0 : 0.01f * v0;
    float v1 = acc[i][1] + b1[cg * 4 + 1]; v1 = v1 > 0.f ? v1 : 0.01f * v1;
    float v2 = acc[i][2] + b1[cg * 4 + 2]; v2 = v2 > 0.f ? v2 : 0.01f * v2;
    float v3 = acc[i][3] + b1[cg * 4 + 3]; v3 = v3 > 0.f ? v3 : 0.01f * v3;
    pk.x = f2bf(v0); pk.y = f2bf(v1); pk.z = f2bf(v2); pk.w = f2bf(v3);
    int rf = (int)rb + rg * 8 + i;            // flat b*T + t
    int b = rf >> 8, tt = rf & 255;
    *(ushort4*)(X1 + ((size_t)tt * ZB + b) * ZEH + cg * 4) = pk;
  }
}

// ---------------------------------------------------------------------------
// half wait: lane l polls flag[gidx][l&31] (agent scope / MALL).
// gidx = bg*2 + hf. Flags 64B-padded.
// ---------------------------------------------------------------------------
__device__ __forceinline__ void qwait(const u32* flags, int gidx, u32 target)
{
  const int l = threadIdx.x & 63;
  const u32* fp = flags + ((size_t)(gidx * 32 + (l & 31))) * 16;
  long long guard = 0;
  for (;;){
    u32 v = __hip_atomic_load(fp, __ATOMIC_RELAXED, __HIP_MEMORY_SCOPE_AGENT);
    if (__ballot(v >= target) == ~0ull) break;
    __builtin_amdgcn_s_sleep(1);
    if (++guard > (1LL << 20)) break;   // fail loud (wrong answer), never hang
  }
}

// ---------------------------------------------------------------------------
// Cooperative LSTM, 2-slot ring (32-row half-tiles): 512 slots total — the
// per-slot fixed cost (~1.4us, measured invariant across r5/r6/r7/r11) is
// amortized over 2x the work. Round-6 protocol (best measured): syncthreads
// slot ends (implicit full drain), publish-after-barrier, qwait poll.
// 256 blocks = 8 bg x 32 hg, 512 thr:
//   waves 0-3 compute: W_hh/Wc slices in regs; per slot 2 m-tiles (40 MFMA),
//     cell, h agent-stores.
//   waves 4-7 stage: poll flag (published end of prev slot), fetch 32KB half
//     tile (MALL), commit swizzled into the idle LDS buffer — all in-slot;
//     the poll+fetch RTTs overlap compute's ~2us of work.
// Slot (t,hf): parity hf; uses h_t[half hf] from hs2[hf]; produces
// h_{t+1}[hf]; stage fetches the half used at slot+1 into hs2[hf^1].
// ---------------------------------------------------------------------------
__global__ __launch_bounds__(512, 1)
void k_lstm(const u16* __restrict__ X1, const u16* __restrict__ Whh,
            const u16* __restrict__ Wcf, const float* __restrict__ bc,
            const u16* __restrict__ Wfcb, const float* __restrict__ bfc,
            u16* __restrict__ hbuf, float* __restrict__ out,
            u32* __restrict__ flags)
{
  __shared__ u16 hs2[2][32 * ZH];   // 2 x 32 KiB, XOR-swizzled half tiles
  const int tid = threadIdx.x;
  const int bg = (int)blockIdx.x >> 5, hg = (int)blockIdx.x & 31;
  const bool isC = (tid < 256);
  const int w = (tid >> 6) & 3, l = tid & 63;
  const int lr = l & 15, lg = l >> 4;
  const int st = tid & 255;
  const int gt = lr >> 2;

  // ---- compute-role persistent state ----
  s8v bwh[16], bwx[4];
  f4v biasv = {0.f, 0.f, 0.f, 0.f};
  float c_reg[2][2][4];   // [hf][m][r] — hf,m are unroll-static (rule 20)
  if (isC){
    const int grow = gt * ZH + hg * 16 + w * 4 + (lr & 3);
    const u16* p = Whh + (size_t)grow * ZH + lg * 8;
    #pragma unroll
    for (int kt = 0; kt < 16; ++kt) bwh[kt] = *(const s8v*)(p + kt * 32);
    const u16* q = Wcf + (size_t)grow * ZEH + lg * 8;
    #pragma unroll
    for (int kt = 0; kt < 4; ++kt) bwx[kt] = *(const s8v*)(q + kt * 32);
    float b = bc[grow];
    biasv[0] = b; biasv[1] = b; biasv[2] = b; biasv[3] = b;
    #pragma unroll
    for (int a = 0; a < 2; ++a){
      #pragma unroll
      for (int m = 0; m < 2; ++m){
        #pragma unroll
        for (int r = 0; r < 4; ++r) c_reg[a][m][r] = 0.f;
      }
    }
  }

  // ---- stage prologue: fetch h_0[half 0] (zeros, buf 0) -> hs2[0] ----
  if (!isC){
    const u64* src = (const u64*)(hbuf + qoff2(0, bg, 0, 0));
    u64 va[8], vb[8];
    #pragma unroll
    for (int i = 0; i < 8; ++i){
      int cc = st + i * 256;
      va[i] = aload(src + (size_t)cc * 2);
      vb[i] = aload(src + (size_t)cc * 2 + 1);
    }
    #pragma unroll
    for (int i = 0; i < 8; ++i){
      int byte = (st + i * 256) * 16;
      int swz = byte ^ (((byte >> 5) & 3) << 4);
      *(s8v*)((char*)hs2[0] + swz) = pair2v(va[i], vb[i]);
    }
  }
  __syncthreads();

  u32* flbase = flags + ((size_t)(bg * 64 + hg)) * 16;   // + hf*512 selects half

  for (int t = 0; t < ZT; ++t){
    #pragma unroll
    for (int hf = 0; hf < 2; ++hf){
      if (isC){
        // X fragments for this slot's 2 m-tiles (t-major; hides under MFMA)
        s8v ax[2][4];
        #pragma unroll
        for (int m = 0; m < 2; ++m){
          const u16* xp = X1 + ((size_t)t * ZB + (bg * 64 + hf * 32 + m * 16 + lr)) * ZEH + lg * 8;
          #pragma unroll
          for (int kt = 0; kt < 4; ++kt) ax[m][kt] = *(const s8v*)(xp + kt * 32);
        }

        const char* hb = (const char*)hs2[hf];
        f4v accm[2];
        #pragma unroll
        for (int m = 0; m < 2; ++m){
          f4v a0 = biasv;
          f4v a1 = {0.f, 0.f, 0.f, 0.f};
          #pragma unroll
          for (int kt = 0; kt < 8; ++kt){
            int byte = (2 * kt + (lg >> 1)) * 1024 + (m * 16 + lr) * 32 + (lg & 1) * 16;
            byte ^= (((byte >> 5) & 3) << 4);
            s8v av = *(const s8v*)(hb + byte);
            a0 = __builtin_amdgcn_mfma_f32_16x16x32_bf16(av, bwh[kt], a0, 0, 0, 0);
          }
          #pragma unroll
          for (int kt = 8; kt < 16; ++kt){
            int byte = (2 * kt + (lg >> 1)) * 1024 + (m * 16 + lr) * 32 + (lg & 1) * 16;
            byte ^= (((byte >> 5) & 3) << 4);
            s8v av = *(const s8v*)(hb + byte);
            a1 = __builtin_amdgcn_mfma_f32_16x16x32_bf16(av, bwh[kt], a1, 0, 0, 0);
          }
          a0 = __builtin_amdgcn_mfma_f32_16x16x32_bf16(ax[m][0], bwx[0], a0, 0, 0, 0);
          a1 = __builtin_amdgcn_mfma_f32_16x16x32_bf16(ax[m][1], bwx[1], a1, 0, 0, 0);
          a0 = __builtin_amdgcn_mfma_f32_16x16x32_bf16(ax[m][2], bwx[2], a0, 0, 0, 0);
          a1 = __builtin_amdgcn_mfma_f32_16x16x32_bf16(ax[m][3], bwx[3], a1, 0, 0, 0);
          accm[m] = a0 + a1;
        }

        // LSTM cell for both m-tiles; h -> global (agent scope)
        u16* hdst = hbuf + qoff2((t + 1) & 1, bg, hf, hg);
        #pragma unroll
        for (int m = 0; m < 2; ++m){
          #pragma unroll
          for (int r = 0; r < 4; ++r){
            float v = accm[m][r];
            float s = (gt == 2) ? 2.f : -1.f;
            float e = __expf(v * s);
            float rc = 1.f / (1.f + e);
            float a = (gt == 2) ? (1.f - 2.f * rc) : rc;   // tanh : sigmoid
            float f_ = __shfl_xor(a, 4);
            float g_ = __shfl_xor(a, 8);
            float o_ = __shfl_xor(a, 12);
            float cv = f_ * c_reg[hf][m][r] + a * g_;
            c_reg[hf][m][r] = cv;
            float e2 = __expf(2.f * cv);
            float hv = o_ * (1.f - 2.f / (1.f + e2));
            u32 bits = f2bf(hv);
            u32 lo = bits | (((u32)__shfl_xor((int)bits, 1)) << 16);
            u32 hi = (u32)__shfl_xor((int)lo, 2);
            if (lr == 0){
              u64 pk = (u64)lo | ((u64)hi << 32);
              __hip_atomic_store((u64*)(hdst + (size_t)(m * 16 + lg * 4 + r) * 16 + w * 4), pk,
                                 __ATOMIC_RELAXED, __HIP_MEMORY_SCOPE_AGENT);
            }
          }
        }
      } else {
        // stage: poll flag for the half used NEXT slot, fetch 32KB, commit.
        // hf==0 -> next slot (t,1) uses h_t[1]:   flag[1] >= t,  buf t&1
        // hf==1 -> next slot (t+1,0) uses h_{t+1}[0]: flag[0] >= t+1, buf (t+1)&1
        const int hfT = hf ^ 1;
        const int tf  = t + hf;
        if (tf < ZT || hf == 0){
          if (!(t == 0 && hf == 0))          // h_0[1] needs no wait (zeros)
            qwait(flags, bg * 2 + hfT, (u32)tf);
          const u64* src = (const u64*)(hbuf + qoff2(tf & 1, bg, hfT, 0));
          u64 va[8], vb[8];
          #pragma unroll
          for (int i = 0; i < 8; ++i){
            int cc = st + i * 256;
            va[i] = aload(src + (size_t)cc * 2);
            vb[i] = aload(src + (size_t)cc * 2 + 1);
          }
          char* dst = (char*)hs2[hf ^ 1];
          #pragma unroll
          for (int i = 0; i < 8; ++i){
            int byte = (st + i * 256) * 16;
            int swz = byte ^ (((byte >> 5) & 3) << 4);
            *(s8v*)(dst + swz) = pair2v(va[i], vb[i]);
          }
        }
      }
      // slot end: full drain (syncthreads) then publish this half's flag
      __syncthreads();
      if (tid == 0)
        __hip_atomic_store(flbase + (size_t)hf * 512, (u32)(t + 1),
                           __ATOMIC_RELAXED, __HIP_MEMORY_SCOPE_AGENT);
    }
  }

  // epilogue: hg==0 blocks compute out = h_T @ Wfc^T + bfc (h_T in buf 0)
  if (hg == 0){
    if (tid < 64){
      qwait(flags, bg * 2 + 0, (u32)ZT);
      qwait(flags, bg * 2 + 1, (u32)ZT);
    }
    __syncthreads();
    if (isC){
      float ob = (lr < ZNC) ? bfc[lr] : 0.f;
      f4v acc = {ob, ob, ob, ob};
      const u16* wp = Wfcb + (size_t)lr * ZH + lg * 8;
      const int hfE = w >> 1;
      const int ric = (w & 1) * 16 + lr;     // row in 32-row chunk
      #pragma unroll
      for (int kt = 0; kt < 16; ++kt){
        int hgp = 2 * kt + (lg >> 1);
        const u64* hp = (const u64*)(hbuf + qoff2(0, bg, hfE, hgp) + (size_t)ric * 16 + (lg & 1) * 8);
        u64 a0 = aload(hp);
        u64 a1 = aload(hp + 1);
        s8v av = pair2v(a0, a1);
        s8v bv = *(const s8v*)(wp + kt * 32);
        acc = __builtin_amdgcn_mfma_f32_16x16x32_bf16(av, bv, acc, 0, 0, 0);
      }
      if (lr < ZNC){
        #pragma unroll
        for (int r = 0; r < 4; ++r)
          out[(size_t)(bg * 64 + w * 16 + lg * 4 + r) * ZNC + lr] = acc[r];
      }
    }
  }
}

// ---------------------------------------------------------------------------
extern "C" void kernel_launch(void* const* d_in, const int* in_sizes, int n_in,
                              void* d_out, int out_size, void* d_ws, size_t ws_size,
                              hipStream_t stream)
{
  const float* seq  = (const float*)d_in[0];
  const float* W1   = (const float*)d_in[1];
  const float* b1   = (const float*)d_in[2];
  const float* W2   = (const float*)d_in[3];
  const float* b2   = (const float*)d_in[4];
  const float* W_ih = (const float*)d_in[5];
  const float* W_hh = (const float*)d_in[6];
  const float* b_ih = (const float*)d_in[7];
  const float* b_hh = (const float*)d_in[8];
  const float* Wfc  = (const float*)d_in[9];
  const float* bfc  = (const float*)d_in[10];
  float* out = (float*)d_out;

  char* ws = (char*)d_ws;
  size_t off = 0;
  auto alloc = [&](size_t bytes){ void* p = ws + off; off += (bytes + 255) & ~(size_t)255; return p; };
  u16*   Wc    = (u16*)  alloc((size_t)ZG * ZEH * 2);
  float* bc    = (float*)alloc((size_t)ZG * 4);
  u16*   Whh   = (u16*)  alloc((size_t)ZG * ZH * 2);
  u16*   Wfcb  = (u16*)  alloc((size_t)16 * ZH * 2);
  u16*   X1    = (u16*)  alloc((size_t)ZB * ZT * ZEH * 2);
  u16*   hbuf  = (u16*)  alloc((size_t)2 * ZB * ZH * 2);
  u32*   flags = (u32*)  alloc((size_t)8 * 2 * 32 * 16 * 4);  // 64B-padded per (bg,hf,hg)

  hipMemsetAsync(flags, 0, (size_t)8 * 2 * 32 * 16 * 4, stream);
  hipMemsetAsync(hbuf, 0, (size_t)ZB * ZH * 2, stream);      // h_0 = 0 (buffer 0)
  hipMemsetAsync(Wfcb, 0, (size_t)16 * ZH * 2, stream);      // pad rows 8..15 = 0

  hipLaunchKernelGGL(k_fold, dim3(ZG), dim3(128), 0, stream, W_ih, W2, b2, b_ih, b_hh, Wc, bc);
  hipLaunchKernelGGL(k_cvt, dim3((ZG * ZH + 255) / 256), dim3(256), 0, stream, W_hh, Whh, ZG * ZH);
  hipLaunchKernelGGL(k_cvt, dim3((ZNC * ZH + 255) / 256), dim3(256), 0, stream, Wfc, Wfcb, ZNC * ZH);
  hipLaunchKernelGGL(k_enc, dim3(ZB * ZT / 64), dim3(256), 0, stream, seq, W1, b1, X1);
  hipLaunchKernelGGL(k_lstm, dim3(NBLK), dim3(512), 0, stream,
                     X1, Whh, Wc, bc, Wfcb, bfc, hbuf, out, flags);
}